// Round 1
// baseline (475.119 us; speedup 1.0000x reference)
//
#include <hip/hip_runtime.h>
#include <hip/hip_bf16.h>
#include <cstdint>

// Problem shape (fixed by setup_inputs)
#define B_DIM 16384
#define U_DIM 512
#define K_DIM 1536   // 3U
#define N_DIM 2560   // 5U

typedef unsigned short u16;
typedef __attribute__((ext_vector_type(2))) unsigned short u16x2;
typedef __attribute__((ext_vector_type(4))) unsigned short u16x4;
typedef __attribute__((ext_vector_type(8))) short bf16x8;   // MFMA A/B frag (4 VGPR)
typedef __attribute__((ext_vector_type(4))) float f32x4;    // MFMA C/D frag

__device__ __forceinline__ u16 f2bf(float f) {
    uint32_t u = __builtin_bit_cast(uint32_t, f);
    u += 0x7FFFu + ((u >> 16) & 1u);   // round-to-nearest-even
    return (u16)(u >> 16);
}
__device__ __forceinline__ float bf2f(u16 h) {
    uint32_t u = ((uint32_t)h) << 16;
    return __builtin_bit_cast(float, u);
}

// ---------------------------------------------------------------------------
// Kernel 1: pack x = concat([inputs, h1, h2], axis=1) -> bf16 [B][3U]
// ---------------------------------------------------------------------------
__global__ void __launch_bounds__(256) cvt_x_kernel(
    const float* __restrict__ inp, const float* __restrict__ h1,
    const float* __restrict__ h2, u16* __restrict__ xb)
{
    int idx = blockIdx.x * 256 + threadIdx.x;       // one float4 per thread
    const int total4 = B_DIM * K_DIM / 4;           // 6291456
    if (idx >= total4) return;
    int e = idx * 4;
    int b = e / K_DIM;
    int k = e - b * K_DIM;
    const float* src;
    if (k < 512)       src = inp + b * 512 + k;
    else if (k < 1024) src = h1  + b * 512 + (k - 512);
    else               src = h2  + b * 512 + (k - 1024);
    float4 v = *(const float4*)src;
    u16x4 o;
    o.x = f2bf(v.x); o.y = f2bf(v.y); o.z = f2bf(v.z); o.w = f2bf(v.w);
    *(u16x4*)(xb + e) = o;
}

// ---------------------------------------------------------------------------
// Kernel 2: wT[n][k] = bf16(w[k][n])   (LDS-tiled transpose, 32x32)
// ---------------------------------------------------------------------------
__global__ void __launch_bounds__(256) cvt_wT_kernel(
    const float* __restrict__ w, u16* __restrict__ wT)
{
    __shared__ float tile[32][33];
    const int n0 = blockIdx.x * 32;   // N
    const int k0 = blockIdx.y * 32;   // K
    const int tx = threadIdx.x & 31;
    const int ty = threadIdx.x >> 5;  // 0..7
#pragma unroll
    for (int i = 0; i < 4; ++i) {
        int kk = ty + i * 8;
        tile[kk][tx] = w[(k0 + kk) * N_DIM + n0 + tx];
    }
    __syncthreads();
#pragma unroll
    for (int i = 0; i < 4; ++i) {
        int nn = ty + i * 8;
        wT[(int64_t)(n0 + nn) * K_DIM + k0 + tx] = f2bf(tile[tx][nn]);
    }
}

// ---------------------------------------------------------------------------
// Kernel 3: GEMM res[M][N] = x[M][K] @ w[K][N] in bf16 MFMA (m97 structure)
//   A = xb [M][K] row-major bf16, Bt = wT [N][K] row-major bf16.
//   128x128 tile, BK=64, 4 waves (2x2), 4x4 16x16x32 frags per wave.
//   global_load_lds width=16 staging, linear LDS (known bank conflicts; T2
//   swizzle is a later round).
// ---------------------------------------------------------------------------
#define BM 128
#define BN 128
#define BK 64

__device__ __forceinline__ void gload_lds16(const void* g, void* l) {
    __builtin_amdgcn_global_load_lds(
        (const __attribute__((address_space(1))) void*)g,
        (__attribute__((address_space(3))) void*)l, 16, 0, 0);
}

__global__ void __launch_bounds__(256) gemm_kernel(
    const u16* __restrict__ A, const u16* __restrict__ Bt,
    u16* __restrict__ C)
{
    __shared__ u16 As[BM * BK];   // [128][64] bf16, 16 KiB
    __shared__ u16 Bs[BN * BK];   // [128][64] bf16, 16 KiB

    const int tid  = threadIdx.x;
    const int lane = tid & 63;
    const int wave = tid >> 6;

    // XCD-aware bijective swizzle (nwg=2560, 2560%8==0)
    const int nwg = 2560;
    int bid = blockIdx.x;
    int swz = (bid & 7) * (nwg / 8) + (bid >> 3);
    const int by = swz / (N_DIM / BN);       // 0..127
    const int bx = swz % (N_DIM / BN);       // 0..19
    const int bm = by * BM;
    const int bn = bx * BN;

    const int wm = (wave >> 1) * 64;
    const int wn = (wave & 1) * 64;

    f32x4 acc[4][4];
#pragma unroll
    for (int i = 0; i < 4; ++i)
#pragma unroll
        for (int j = 0; j < 4; ++j) acc[i][j] = (f32x4)(0.0f);

    // staging: chunk = i*256 + wave*64 + lane ; row = chunk/8 ; k8 = chunk%8
    const int chunk0 = wave * 64 + lane;

    for (int kt = 0; kt < K_DIM; kt += BK) {
#pragma unroll
        for (int i = 0; i < 4; ++i) {
            int ch  = i * 256 + chunk0;
            int row = ch >> 3;
            int c8  = ch & 7;
            const u16* ga = A  + (int64_t)(bm + row) * K_DIM + kt + c8 * 8;
            const u16* gb = Bt + (int64_t)(bn + row) * K_DIM + kt + c8 * 8;
            char* la = (char*)As + (i * 256 + wave * 64) * 16; // wave-uniform base
            char* lb = (char*)Bs + (i * 256 + wave * 64) * 16;
            gload_lds16(ga, la);
            gload_lds16(gb, lb);
        }
        __syncthreads();

#pragma unroll
        for (int ks = 0; ks < 2; ++ks) {
            bf16x8 af[4], bfr[4];
#pragma unroll
            for (int m = 0; m < 4; ++m)
                af[m] = *(const bf16x8*)&As[(wm + m * 16 + (lane & 15)) * BK +
                                            ks * 32 + (lane >> 4) * 8];
#pragma unroll
            for (int n = 0; n < 4; ++n)
                bfr[n] = *(const bf16x8*)&Bs[(wn + n * 16 + (lane & 15)) * BK +
                                             ks * 32 + (lane >> 4) * 8];
#pragma unroll
            for (int m = 0; m < 4; ++m)
#pragma unroll
                for (int n = 0; n < 4; ++n)
                    acc[m][n] = __builtin_amdgcn_mfma_f32_16x16x32_bf16(
                        af[m], bfr[n], acc[m][n], 0, 0, 0);
        }
        __syncthreads();
    }

    // epilogue: C/D layout col=lane&15, row=(lane>>4)*4+r  [m89-verified]
    const int col0 = lane & 15;
    const int row0 = (lane >> 4) * 4;
#pragma unroll
    for (int m = 0; m < 4; ++m)
#pragma unroll
        for (int n = 0; n < 4; ++n)
#pragma unroll
            for (int r = 0; r < 4; ++r) {
                int grow = bm + wm + m * 16 + row0 + r;
                int gcol = bn + wn + n * 16 + col0;
                C[(int64_t)grow * N_DIM + gcol] = f2bf(acc[m][n][r]);
            }
}

// ---------------------------------------------------------------------------
// Kernel 4: per-row LayerNorm (per gate over U=512) + LSTM pointwise
//   one block (256 thr) per batch row; each thread owns u = t*2, t*2+1
// ---------------------------------------------------------------------------
__global__ void __launch_bounds__(256) ln_pointwise_kernel(
    const u16*  __restrict__ res,  const float* __restrict__ bias,
    const float* __restrict__ c1,  const float* __restrict__ c2,
    const float* __restrict__ nw,  const float* __restrict__ nb,
    float* __restrict__ out)
{
    const int b    = blockIdx.x;
    const int t    = threadIdx.x;
    const int lane = t & 63;
    const int wave = t >> 6;

    __shared__ float2 part[5][4];

    const u16* row = res + (int64_t)b * N_DIM;
    float v[5][2];

#pragma unroll
    for (int g = 0; g < 5; ++g) {
        u16x2  raw = *(const u16x2*)(row + g * 512 + t * 2);
        float2 bb  = *(const float2*)(bias + g * 512 + t * 2);
        v[g][0] = bf2f(raw.x) + bb.x;
        v[g][1] = bf2f(raw.y) + bb.y;
        float s = v[g][0] + v[g][1];
        float q = v[g][0] * v[g][0] + v[g][1] * v[g][1];
#pragma unroll
        for (int off = 32; off >= 1; off >>= 1) {
            s += __shfl_xor(s, off);
            q += __shfl_xor(q, off);
        }
        if (lane == 0) part[g][wave] = make_float2(s, q);
    }
    __syncthreads();

    float mean[5], rstd[5];
#pragma unroll
    for (int g = 0; g < 5; ++g) {
        float s = part[g][0].x + part[g][1].x + part[g][2].x + part[g][3].x;
        float q = part[g][0].y + part[g][1].y + part[g][2].y + part[g][3].y;
        float m   = s * (1.0f / 512.0f);
        float var = q * (1.0f / 512.0f) - m * m;
        mean[g] = m;
        rstd[g] = rsqrtf(var + 1e-5f);
    }

    float lnv[5][2];
#pragma unroll
    for (int g = 0; g < 5; ++g) {
        float2 w2 = *(const float2*)(nw + g * 512 + t * 2);
        float2 b2 = *(const float2*)(nb + g * 512 + t * 2);
        lnv[g][0] = (v[g][0] - mean[g]) * rstd[g] * w2.x + b2.x;
        lnv[g][1] = (v[g][1] - mean[g]) * rstd[g] * w2.y + b2.y;
    }

    float2 c1v = *(const float2*)(c1 + (int64_t)b * 512 + t * 2);
    float2 c2v = *(const float2*)(c2 + (int64_t)b * 512 + t * 2);

#pragma unroll
    for (int e = 0; e < 2; ++e) {
        float ig  = 1.0f / (1.0f + expf(-lnv[0][e]));
        float jg  = tanhf(lnv[1][e]);
        float fg  = 1.0f / (1.0f + expf(-lnv[2][e]));
        float f2g = 1.0f / (1.0f + expf(-lnv[3][e]));
        float og  = 1.0f / (1.0f + expf(-lnv[4][e]));
        float c1s = e ? c1v.y : c1v.x;
        float c2s = e ? c2v.y : c2v.x;
        float cc = c1s * fg + c2s * f2g + ig * jg;
        float hh = cc * og;
        int64_t o = (int64_t)b * 512 + t * 2 + e;
        out[o] = cc;
        out[(int64_t)B_DIM * U_DIM + o] = hh;
    }
}

// ---------------------------------------------------------------------------
extern "C" void kernel_launch(void* const* d_in, const int* in_sizes, int n_in,
                              void* d_out, int out_size, void* d_ws, size_t ws_size,
                              hipStream_t stream)
{
    const float* inputs = (const float*)d_in[0];
    const float* c1     = (const float*)d_in[1];
    const float* h1     = (const float*)d_in[2];
    const float* c2     = (const float*)d_in[3];
    const float* h2     = (const float*)d_in[4];
    const float* w      = (const float*)d_in[5];
    const float* bias   = (const float*)d_in[6];
    const float* nw     = (const float*)d_in[7];
    const float* nb     = (const float*)d_in[8];
    float* out = (float*)d_out;

    // workspace layout (total 142,082,048 B)
    const size_t XB_BYTES = (size_t)B_DIM * K_DIM * 2;   // 50331648
    const size_t WT_BYTES = (size_t)N_DIM * K_DIM * 2;   // 7864320
    u16* xb  = (u16*)d_ws;
    u16* wT  = (u16*)((char*)d_ws + XB_BYTES);
    u16* res = (u16*)((char*)d_ws + XB_BYTES + WT_BYTES);

    cvt_x_kernel<<<(B_DIM * K_DIM / 4 + 255) / 256, 256, 0, stream>>>(inputs, h1, h2, xb);
    cvt_wT_kernel<<<dim3(N_DIM / 32, K_DIM / 32), 256, 0, stream>>>(w, wT);
    gemm_kernel<<<(B_DIM / BM) * (N_DIM / BN), 256, 0, stream>>>(xb, wT, res);
    ln_pointwise_kernel<<<B_DIM, 256, 0, stream>>>(res, bias, c1, c2, nw, nb, out);
}

// Round 2
// 391.560 us; speedup vs baseline: 1.2134x; 1.2134x over previous
//
#include <hip/hip_runtime.h>
#include <hip/hip_bf16.h>
#include <cstdint>

// Problem shape (fixed by setup_inputs)
#define B_DIM 16384
#define U_DIM 512
#define K_DIM 1536   // 3U
#define N_DIM 2560   // 5U
#define NT    24     // K-tiles (K_DIM / 64)

typedef unsigned short u16;
typedef __attribute__((ext_vector_type(4))) unsigned short u16x4;
typedef __attribute__((ext_vector_type(8))) unsigned short u16x8;
typedef __attribute__((ext_vector_type(8))) short bf16x8;   // MFMA A/B frag (4 VGPR)
typedef __attribute__((ext_vector_type(4))) float f32x4;    // MFMA C/D frag

__device__ __forceinline__ u16 f2bf(float f) {
    uint32_t u = __builtin_bit_cast(uint32_t, f);
    u += 0x7FFFu + ((u >> 16) & 1u);   // round-to-nearest-even
    return (u16)(u >> 16);
}
__device__ __forceinline__ float bf2f(u16 h) {
    uint32_t u = ((uint32_t)h) << 16;
    return __builtin_bit_cast(float, u);
}

// ---------------------------------------------------------------------------
// Kernel 1: pack x = concat([inputs, h1, h2], axis=1) -> bf16 [B][3U]
// ---------------------------------------------------------------------------
__global__ void __launch_bounds__(256) cvt_x_kernel(
    const float* __restrict__ inp, const float* __restrict__ h1,
    const float* __restrict__ h2, u16* __restrict__ xb)
{
    int idx = blockIdx.x * 256 + threadIdx.x;       // one float4 per thread
    const int total4 = B_DIM * K_DIM / 4;
    if (idx >= total4) return;
    int e = idx * 4;
    int b = e / K_DIM;
    int k = e - b * K_DIM;
    const float* src;
    if (k < 512)       src = inp + b * 512 + k;
    else if (k < 1024) src = h1  + b * 512 + (k - 512);
    else               src = h2  + b * 512 + (k - 1024);
    float4 v = *(const float4*)src;
    u16x4 o;
    o.x = f2bf(v.x); o.y = f2bf(v.y); o.z = f2bf(v.z); o.w = f2bf(v.w);
    *(u16x4*)(xb + e) = o;
}

// ---------------------------------------------------------------------------
// Kernel 2: wT[n][k] = bf16(w[k][n])   (LDS-tiled transpose, 32x32)
// ---------------------------------------------------------------------------
__global__ void __launch_bounds__(256) cvt_wT_kernel(
    const float* __restrict__ w, u16* __restrict__ wT)
{
    __shared__ float tile[32][33];
    const int n0 = blockIdx.x * 32;   // N
    const int k0 = blockIdx.y * 32;   // K
    const int tx = threadIdx.x & 31;
    const int ty = threadIdx.x >> 5;  // 0..7
#pragma unroll
    for (int i = 0; i < 4; ++i) {
        int kk = ty + i * 8;
        tile[kk][tx] = w[(k0 + kk) * N_DIM + n0 + tx];
    }
    __syncthreads();
#pragma unroll
    for (int i = 0; i < 4; ++i) {
        int nn = ty + i * 8;
        wT[(int64_t)(n0 + nn) * K_DIM + k0 + tx] = f2bf(tile[tx][nn]);
    }
}

// ---------------------------------------------------------------------------
// Kernel 3: GEMM res = x @ w, 256x256 tile, BK=64, 8 waves, 8-phase schedule
//   (4 phases per K-tile x 2-tile ping-pong), K-half staging, pair-packed
//   XOR LDS swizzle, counted vmcnt(4), setprio around MFMA.
//   LDS layout: sm[buf(2)][A/B(2)][ks(2)][8192 u16]  = 128 KiB
//     within a K-half: line = row>>1 (128B lines), 16B slot
//     s = (((row&1)<<2)|c) ^ (line&7), c = k-chunk (8 bf16)
// ---------------------------------------------------------------------------
__device__ __forceinline__ void gload_lds16(const void* g, void* l) {
    __builtin_amdgcn_global_load_lds(
        (const __attribute__((address_space(1))) void*)g,
        (__attribute__((address_space(3))) void*)l, 16, 0, 0);
}

#define BAR    __builtin_amdgcn_s_barrier()
#define FENCE  asm volatile("" ::: "memory")
#define VMCNT4 asm volatile("s_waitcnt vmcnt(4)" ::: "memory")
#define LGKM0  do { asm volatile("s_waitcnt lgkmcnt(0)" ::: "memory"); \
                    __builtin_amdgcn_sched_barrier(0); } while (0)

__global__ void __launch_bounds__(512, 2) gemm_kernel(
    const u16* __restrict__ A, const u16* __restrict__ Bt,
    u16* __restrict__ C)
{
    __shared__ u16 sm[65536];   // 128 KiB

    const int tid  = threadIdx.x;
    const int lane = tid & 63;
    const int wave = tid >> 6;

    // T1: XCD-aware bijective swizzle (nwg=640, 640%8==0)
    int bid = blockIdx.x;
    int swz = (bid & 7) * 80 + (bid >> 3);
    const int bm = (swz / 10) * 256;
    const int bn = (swz % 10) * 256;

    const int wm = (wave >> 2) * 128;   // 2 waves in M
    const int wn = (wave & 3) * 64;     // 4 waves in N

    // ---- LDS read addressing (swizzled) ----
    const int l15 = lane & 15, cq = lane >> 4;
    const int s   = (((l15 & 1) << 2) | cq) ^ ((l15 >> 1) & 7);
    const int rdA = ((wm >> 1) + (l15 >> 1)) * 64 + s * 8;   // + m*512 + ks*8192
    const int rdB = ((wn >> 1) + (l15 >> 1)) * 64 + s * 8;   // + n*512 + ks*8192

    // ---- staging addressing (inverse-swizzled global source, linear LDS) ----
    const int line0 = tid >> 3;
    const int sl0   = (tid & 7) ^ (line0 & 7);
    const int srow  = line0 * 2 + (sl0 >> 2);
    const int sc8   = (sl0 & 3) * 8;
    const u16* gA = A  + (int64_t)(bm + srow) * K_DIM + sc8;
    const u16* gB = Bt + (int64_t)(bn + srow) * K_DIM + sc8;
    char* ld0 = (char*)sm + tid * 16;

#define STAGE(ab, ks, kt, buf) do {                                        \
        const u16* g_ = ((ab) ? gB : gA) + (kt) + (ks) * 32;               \
        char* d_ = ld0 + (buf) * 65536 + (ab) * 32768 + (ks) * 16384;      \
        gload_lds16(g_, d_);                                               \
        gload_lds16(g_ + 128 * K_DIM, d_ + 8192);                          \
    } while (0)

    f32x4 acc[8][4];
#pragma unroll
    for (int i = 0; i < 8; ++i)
#pragma unroll
        for (int j = 0; j < 4; ++j) acc[i][j] = (f32x4)(0.0f);

    // prologue: stage all 4 halves of tile 0 into buf 0
    STAGE(0, 0, 0, 0);   // A ks0
    STAGE(1, 0, 0, 0);   // B ks0
    STAGE(0, 1, 0, 0);   // A ks1
    STAGE(1, 1, 0, 0);   // B ks1
    VMCNT4;              // A/B ks0 landed; ks1 may be in flight
    BAR; FENCE;

    bf16x8 af[4], bfr[4];

#define LOAD_A4(BASE) _Pragma("unroll")                                    \
    for (int mi = 0; mi < 4; ++mi) af[mi] = *(const bf16x8*)((BASE) + mi * 512)
#define LOAD_B4(BASE) _Pragma("unroll")                                    \
    for (int n = 0; n < 4; ++n) bfr[n] = *(const bf16x8*)((BASE) + n * 512)
#define MFMA16(MB) _Pragma("unroll")                                       \
    for (int mi = 0; mi < 4; ++mi) { _Pragma("unroll")                     \
        for (int n = 0; n < 4; ++n)                                        \
            acc[(MB) + mi][n] = __builtin_amdgcn_mfma_f32_16x16x32_bf16(   \
                af[mi], bfr[n], acc[(MB) + mi][n], 0, 0, 0); }

    for (int t = 0; t < NT; ++t) {
        const int cur = t & 1, nxt = cur ^ 1;
        const int ktn = ((t + 1) == NT) ? 0 : (t + 1) * 64;  // wrap: uniform sched
        const u16* aB = sm + cur * 32768 + rdA;           // A base (+ks*8192)
        const u16* bB = sm + cur * 32768 + 16384 + rdB;   // B base (+ks*8192)

        // phase 0: m0-3 x ks0  (reads A-K0 + B-K0: staged 4 and 3 phases ago)
        LOAD_A4(aB);
        LOAD_B4(bB);
        STAGE(0, 0, ktn, nxt);          // A-K0 of t+1
        BAR; LGKM0;
        __builtin_amdgcn_s_setprio(1);
        MFMA16(0);
        __builtin_amdgcn_s_setprio(0);
        BAR; FENCE;

        // phase 1: m4-7 x ks0
        LOAD_A4(aB + 4 * 512);
        STAGE(1, 0, ktn, nxt);          // B-K0 of t+1
        BAR; LGKM0;
        __builtin_amdgcn_s_setprio(1);
        MFMA16(4);
        __builtin_amdgcn_s_setprio(0);
        VMCNT4;                          // A-K1/B-K1 of t landed (for phase 2)
        BAR; FENCE;

        // phase 2: m0-3 x ks1
        LOAD_A4(aB + 8192);
        LOAD_B4(bB + 8192);
        STAGE(0, 1, ktn, nxt);          // A-K1 of t+1
        BAR; LGKM0;
        __builtin_amdgcn_s_setprio(1);
        MFMA16(0);
        __builtin_amdgcn_s_setprio(0);
        BAR; FENCE;

        // phase 3: m4-7 x ks1
        LOAD_A4(aB + 8192 + 4 * 512);
        STAGE(1, 1, ktn, nxt);          // B-K1 of t+1
        BAR; LGKM0;
        __builtin_amdgcn_s_setprio(1);
        MFMA16(4);
        __builtin_amdgcn_s_setprio(0);
        VMCNT4;                          // A-K0/B-K0 of t+1 landed (for next ph0)
        BAR; FENCE;
    }

    // epilogue: C/D layout col=lane&15, row=(lane>>4)*4+r  [m89-verified]
    const int ecol = lane & 15;
    const int erow = (lane >> 4) * 4;
#pragma unroll
    for (int m = 0; m < 8; ++m)
#pragma unroll
        for (int n = 0; n < 4; ++n)
#pragma unroll
            for (int r = 0; r < 4; ++r) {
                int grow = bm + wm + m * 16 + erow + r;
                int gcol = bn + wn + n * 16 + ecol;
                C[(int64_t)grow * N_DIM + gcol] = f2bf(acc[m][n][r]);
            }
}

// ---------------------------------------------------------------------------
// Kernel 4: per-row LayerNorm (per gate over U=512) + LSTM pointwise
//   one WAVE per batch row (4 rows / 256-thr block); 16B/lane loads,
//   butterfly shuffle reduce, no LDS, float4 stores.
// ---------------------------------------------------------------------------
__global__ void __launch_bounds__(256) ln_pointwise_kernel(
    const u16*  __restrict__ res,  const float* __restrict__ bias,
    const float* __restrict__ c1,  const float* __restrict__ c2,
    const float* __restrict__ nw,  const float* __restrict__ nb,
    float* __restrict__ out)
{
    const int wave = threadIdx.x >> 6;
    const int lane = threadIdx.x & 63;
    const int b    = blockIdx.x * 4 + wave;
    const u16* row = res + (int64_t)b * N_DIM;
    const int u0 = lane * 8;

    float v[5][8];
    float rstd[5], mean[5];

#pragma unroll
    for (int g = 0; g < 5; ++g) {
        u16x8 raw = *(const u16x8*)(row + g * 512 + u0);
        const float4* bp = (const float4*)(bias + g * 512 + u0);
        float4 b0 = bp[0], b1 = bp[1];
        v[g][0] = bf2f(raw[0]) + b0.x;  v[g][1] = bf2f(raw[1]) + b0.y;
        v[g][2] = bf2f(raw[2]) + b0.z;  v[g][3] = bf2f(raw[3]) + b0.w;
        v[g][4] = bf2f(raw[4]) + b1.x;  v[g][5] = bf2f(raw[5]) + b1.y;
        v[g][6] = bf2f(raw[6]) + b1.z;  v[g][7] = bf2f(raw[7]) + b1.w;
        float s = 0.f, q = 0.f;
#pragma unroll
        for (int j = 0; j < 8; ++j) { s += v[g][j]; q += v[g][j] * v[g][j]; }
#pragma unroll
        for (int off = 1; off < 64; off <<= 1) {
            s += __shfl_xor(s, off);
            q += __shfl_xor(q, off);
        }
        float m   = s * (1.0f / 512.0f);
        float var = q * (1.0f / 512.0f) - m * m;
        mean[g] = m;
        rstd[g] = rsqrtf(var + 1e-5f);
    }

#pragma unroll
    for (int g = 0; g < 5; ++g) {
        const float4* wp = (const float4*)(nw + g * 512 + u0);
        const float4* bp = (const float4*)(nb + g * 512 + u0);
        float4 w0 = wp[0], w1 = wp[1], n0 = bp[0], n1 = bp[1];
        float ws[8] = {w0.x, w0.y, w0.z, w0.w, w1.x, w1.y, w1.z, w1.w};
        float ns[8] = {n0.x, n0.y, n0.z, n0.w, n1.x, n1.y, n1.z, n1.w};
#pragma unroll
        for (int j = 0; j < 8; ++j)
            v[g][j] = (v[g][j] - mean[g]) * rstd[g] * ws[j] + ns[j];
    }

    const float4* c1p = (const float4*)(c1 + (int64_t)b * 512 + u0);
    const float4* c2p = (const float4*)(c2 + (int64_t)b * 512 + u0);
    float4 c1a = c1p[0], c1b = c1p[1], c2a = c2p[0], c2b = c2p[1];
    float c1s[8] = {c1a.x, c1a.y, c1a.z, c1a.w, c1b.x, c1b.y, c1b.z, c1b.w};
    float c2s[8] = {c2a.x, c2a.y, c2a.z, c2a.w, c2b.x, c2b.y, c2b.z, c2b.w};

    float oc[8], oh[8];
#pragma unroll
    for (int j = 0; j < 8; ++j) {
        float ig  = 1.0f / (1.0f + expf(-v[0][j]));
        float jg  = tanhf(v[1][j]);
        float fg  = 1.0f / (1.0f + expf(-v[2][j]));
        float f2g = 1.0f / (1.0f + expf(-v[3][j]));
        float og  = 1.0f / (1.0f + expf(-v[4][j]));
        float cc  = c1s[j] * fg + c2s[j] * f2g + ig * jg;
        oc[j] = cc;
        oh[j] = cc * og;
    }

    float* oC = out + (int64_t)b * 512 + u0;
    float* oH = out + (int64_t)B_DIM * U_DIM + (int64_t)b * 512 + u0;
    ((float4*)oC)[0] = make_float4(oc[0], oc[1], oc[2], oc[3]);
    ((float4*)oC)[1] = make_float4(oc[4], oc[5], oc[6], oc[7]);
    ((float4*)oH)[0] = make_float4(oh[0], oh[1], oh[2], oh[3]);
    ((float4*)oH)[1] = make_float4(oh[4], oh[5], oh[6], oh[7]);
}

// ---------------------------------------------------------------------------
extern "C" void kernel_launch(void* const* d_in, const int* in_sizes, int n_in,
                              void* d_out, int out_size, void* d_ws, size_t ws_size,
                              hipStream_t stream)
{
    const float* inputs = (const float*)d_in[0];
    const float* c1     = (const float*)d_in[1];
    const float* h1     = (const float*)d_in[2];
    const float* c2     = (const float*)d_in[3];
    const float* h2     = (const float*)d_in[4];
    const float* w      = (const float*)d_in[5];
    const float* bias   = (const float*)d_in[6];
    const float* nw     = (const float*)d_in[7];
    const float* nb     = (const float*)d_in[8];
    float* out = (float*)d_out;

    const size_t XB_BYTES = (size_t)B_DIM * K_DIM * 2;   // 50331648
    const size_t WT_BYTES = (size_t)N_DIM * K_DIM * 2;   // 7864320
    u16* xb  = (u16*)d_ws;
    u16* wT  = (u16*)((char*)d_ws + XB_BYTES);
    u16* res = (u16*)((char*)d_ws + XB_BYTES + WT_BYTES);

    cvt_x_kernel<<<(B_DIM * K_DIM / 4 + 255) / 256, 256, 0, stream>>>(inputs, h1, h2, xb);
    cvt_wT_kernel<<<dim3(N_DIM / 32, K_DIM / 32), 256, 0, stream>>>(w, wT);
    gemm_kernel<<<(B_DIM / 256) * (N_DIM / 256), 512, 0, stream>>>(xb, wT, res);
    ln_pointwise_kernel<<<B_DIM / 4, 256, 0, stream>>>(res, bias, c1, c2, nw, nb, out);
}

// Round 3
// 383.105 us; speedup vs baseline: 1.2402x; 1.0221x over previous
//
#include <hip/hip_runtime.h>
#include <hip/hip_bf16.h>
#include <cstdint>

// Problem shape (fixed by setup_inputs)
#define B_DIM 16384
#define U_DIM 512
#define K_DIM 1536   // 3U
#define N_DIM 2560   // 5U
#define NT    24     // K-tiles (K_DIM / 64)

typedef unsigned short u16;
typedef __attribute__((ext_vector_type(4))) unsigned short u16x4;
typedef __attribute__((ext_vector_type(8))) unsigned short u16x8;
typedef __attribute__((ext_vector_type(8))) short bf16x8;   // MFMA A/B frag (4 VGPR)
typedef __attribute__((ext_vector_type(4))) float f32x4;    // MFMA C/D frag

__device__ __forceinline__ u16 f2bf(float f) {
    uint32_t u = __builtin_bit_cast(uint32_t, f);
    u += 0x7FFFu + ((u >> 16) & 1u);   // round-to-nearest-even
    return (u16)(u >> 16);
}
__device__ __forceinline__ float bf2f(u16 h) {
    uint32_t u = ((uint32_t)h) << 16;
    return __builtin_bit_cast(float, u);
}

// ---------------------------------------------------------------------------
// Kernel 1: pack x = concat([inputs, h1, h2], axis=1) -> bf16 [B][3U]
// ---------------------------------------------------------------------------
__global__ void __launch_bounds__(256) cvt_x_kernel(
    const float* __restrict__ inp, const float* __restrict__ h1,
    const float* __restrict__ h2, u16* __restrict__ xb)
{
    int idx = blockIdx.x * 256 + threadIdx.x;       // one float4 per thread
    const int total4 = B_DIM * K_DIM / 4;
    if (idx >= total4) return;
    int e = idx * 4;
    int b = e / K_DIM;
    int k = e - b * K_DIM;
    const float* src;
    if (k < 512)       src = inp + b * 512 + k;
    else if (k < 1024) src = h1  + b * 512 + (k - 512);
    else               src = h2  + b * 512 + (k - 1024);
    float4 v = *(const float4*)src;
    u16x4 o;
    o.x = f2bf(v.x); o.y = f2bf(v.y); o.z = f2bf(v.z); o.w = f2bf(v.w);
    *(u16x4*)(xb + e) = o;
}

// ---------------------------------------------------------------------------
// Kernel 2: wT[n][k] = bf16(w[k][n])   (LDS-tiled transpose, 32x32)
// ---------------------------------------------------------------------------
__global__ void __launch_bounds__(256) cvt_wT_kernel(
    const float* __restrict__ w, u16* __restrict__ wT)
{
    __shared__ float tile[32][33];
    const int n0 = blockIdx.x * 32;   // N
    const int k0 = blockIdx.y * 32;   // K
    const int tx = threadIdx.x & 31;
    const int ty = threadIdx.x >> 5;  // 0..7
#pragma unroll
    for (int i = 0; i < 4; ++i) {
        int kk = ty + i * 8;
        tile[kk][tx] = w[(k0 + kk) * N_DIM + n0 + tx];
    }
    __syncthreads();
#pragma unroll
    for (int i = 0; i < 4; ++i) {
        int nn = ty + i * 8;
        wT[(int64_t)(n0 + nn) * K_DIM + k0 + tx] = f2bf(tile[tx][nn]);
    }
}

// ---------------------------------------------------------------------------
// Kernel 3: GEMM res = x @ w. Tile 128x256, BK=64, 8 waves (2M x 4N, 64x64
//   each), nwg = 128*10 = 1280 = 5 EXACT rounds on 256 CUs (no ragged round).
//   2 phases per K-tile, 16 MFMA + 8 ds_read_b128 + 3 global_load_lds per
//   phase, counted vmcnt(3) at every phase end (never 0), pair-packed XOR
//   LDS swizzle (conflict-free, verified 0 conflicts in r2), setprio(1)
//   around the MFMA cluster.
//   LDS: sm[buf(2)][ A 128x64 (2 K-halves of 4096 u16) | B 256x64 (2 K-halves
//   of 8192 u16) ] = 96 KiB. Within a K-half (rows x 32 u16): 128B line =
//   2 rows; 16B slot s = (((row&1)<<2)|c) ^ ((row>>1)&7), c = k-chunk of 8.
//   Staged via inverse-swizzled GLOBAL source + linear LDS dest (rule #21).
// ---------------------------------------------------------------------------
__device__ __forceinline__ void gload_lds16(const void* g, void* l) {
    __builtin_amdgcn_global_load_lds(
        (const __attribute__((address_space(1))) void*)g,
        (__attribute__((address_space(3))) void*)l, 16, 0, 0);
}

#define BAR    __builtin_amdgcn_s_barrier()
#define FENCE  asm volatile("" ::: "memory")
#define VMCNT3 asm volatile("s_waitcnt vmcnt(3)" ::: "memory")
#define LGKM0  do { asm volatile("s_waitcnt lgkmcnt(0)" ::: "memory"); \
                    __builtin_amdgcn_sched_barrier(0); } while (0)

__global__ void __launch_bounds__(512, 2) gemm_kernel(
    const u16* __restrict__ A, const u16* __restrict__ Bt,
    u16* __restrict__ C)
{
    __shared__ u16 sm[49152];   // 96 KiB: per buf 24576 u16 (A 8192 | B 16384)

    const int tid  = threadIdx.x;
    const int lane = tid & 63;
    const int wave = tid >> 6;

    // T1: XCD-aware bijective swizzle (nwg=1280, 1280%8==0)
    int bid = blockIdx.x;
    int swz = (bid & 7) * 160 + (bid >> 3);
    const int bm = (swz / 10) * 128;   // 128 m-tiles
    const int bn = (swz % 10) * 256;   // 10 n-tiles

    const int wm = (wave >> 2) * 64;   // 2 waves in M
    const int wn = (wave & 3) * 64;    // 4 waves in N

    // ---- LDS read addressing (swizzled) ----
    const int l15 = lane & 15, cq = lane >> 4;
    const int s   = (((l15 & 1) << 2) | cq) ^ ((l15 >> 1) & 7);
    const int rdA = ((wm + l15) >> 1) * 64 + s * 8;   // + mi*512 + ks*4096
    const int rdB = ((wn + l15) >> 1) * 64 + s * 8;   // + n*512  + ks*8192

    // ---- staging addressing (inverse-swizzled global src, linear LDS dst) ----
    const int line0 = tid >> 3;
    const int rc    = (tid & 7) ^ (line0 & 7);
    const int srow  = line0 * 2 + (rc >> 2);
    const int sc8   = (rc & 3) * 8;
    const u16* gA = A  + (int64_t)(bm + srow) * K_DIM + sc8;   // A: 1 chunk/thr
    const u16* gB = Bt + (int64_t)(bn + srow) * K_DIM + sc8;   // B: rows srow, srow+128
    char* ldA = (char*)sm + tid * 16;             // A half base (bytes)
    char* ldB = (char*)sm + 16384 + tid * 16;     // B half base (bytes)

#define STAGE(ks, kt, buf) do {                                            \
        const u16* ga_ = gA + (kt) + (ks) * 32;                            \
        const u16* gb_ = gB + (kt) + (ks) * 32;                            \
        char* la_ = ldA + (buf) * 49152 + (ks) * 8192;                     \
        char* lb_ = ldB + (buf) * 49152 + (ks) * 16384;                    \
        gload_lds16(ga_, la_);                                             \
        gload_lds16(gb_, lb_);                                             \
        gload_lds16(gb_ + 128 * K_DIM, lb_ + 8192);                        \
    } while (0)

    f32x4 acc[4][4];
#pragma unroll
    for (int i = 0; i < 4; ++i)
#pragma unroll
        for (int j = 0; j < 4; ++j) acc[i][j] = (f32x4)(0.0f);

    // prologue: stage both K-halves of tile 0 into buf 0 (6 loads)
    STAGE(0, 0, 0);
    STAGE(1, 0, 0);
    VMCNT3;              // K-half 0 landed; K-half 1 may be in flight
    BAR; FENCE;

    bf16x8 af[4], bfr[4];

#define LOAD_A4(BASE) _Pragma("unroll")                                    \
    for (int mi = 0; mi < 4; ++mi) af[mi] = *(const bf16x8*)((BASE) + mi * 512)
#define LOAD_B4(BASE) _Pragma("unroll")                                    \
    for (int n = 0; n < 4; ++n) bfr[n] = *(const bf16x8*)((BASE) + n * 512)
#define MFMA16 _Pragma("unroll")                                           \
    for (int mi = 0; mi < 4; ++mi) { _Pragma("unroll")                     \
        for (int n = 0; n < 4; ++n)                                        \
            acc[mi][n] = __builtin_amdgcn_mfma_f32_16x16x32_bf16(          \
                af[mi], bfr[n], acc[mi][n], 0, 0, 0); }

    for (int t = 0; t < NT; ++t) {
        const int cur = t & 1, nxt = cur ^ 1;
        const int ktn = ((t + 1) == NT) ? 0 : (t + 1) * 64;  // wrap: uniform
        const u16* base = sm + cur * 24576;

        // phase 0 (ks=0): reads staged >=2 phases ago; stages t+1 K-half 0
        LOAD_A4(base + rdA);
        LOAD_B4(base + 8192 + rdB);
        STAGE(0, ktn, nxt);
        BAR; LGKM0;
        __builtin_amdgcn_s_setprio(1);
        MFMA16;
        __builtin_amdgcn_s_setprio(0);
        VMCNT3;          // previous phase's 3 loads landed (next phase's data)
        BAR; FENCE;

        // phase 1 (ks=1): stages t+1 K-half 1
        LOAD_A4(base + 4096 + rdA);
        LOAD_B4(base + 8192 + 8192 + rdB);
        STAGE(1, ktn, nxt);
        BAR; LGKM0;
        __builtin_amdgcn_s_setprio(1);
        MFMA16;
        __builtin_amdgcn_s_setprio(0);
        VMCNT3;          // t+1 K-half 0 landed (for next ph0 reads)
        BAR; FENCE;
    }

    // epilogue: C/D layout col=lane&15, row=(lane>>4)*4+r  [m89-verified]
    const int ecol = lane & 15;
    const int erow = (lane >> 4) * 4;
#pragma unroll
    for (int m = 0; m < 4; ++m)
#pragma unroll
        for (int n = 0; n < 4; ++n)
#pragma unroll
            for (int r = 0; r < 4; ++r) {
                int grow = bm + wm + m * 16 + erow + r;
                int gcol = bn + wn + n * 16 + ecol;
                C[(int64_t)grow * N_DIM + gcol] = f2bf(acc[m][n][r]);
            }
}

// ---------------------------------------------------------------------------
// Kernel 4: per-row LayerNorm (per gate over U=512) + LSTM pointwise
//   one WAVE per batch row; 16B/lane loads, butterfly shuffle reduce,
//   fast-exp activations (overflow-safe), float4 stores.
// ---------------------------------------------------------------------------
__device__ __forceinline__ float fsig(float x) {
    return 1.0f / (1.0f + __expf(-x));          // x bounded ~ +-25 post-LN
}
__device__ __forceinline__ float ftanh(float x) {
    float e = __expf(-2.0f * fabsf(x));         // e in (0,1], no overflow
    float r = (1.0f - e) / (1.0f + e);
    return copysignf(r, x);
}

__global__ void __launch_bounds__(256) ln_pointwise_kernel(
    const u16*  __restrict__ res,  const float* __restrict__ bias,
    const float* __restrict__ c1,  const float* __restrict__ c2,
    const float* __restrict__ nw,  const float* __restrict__ nb,
    float* __restrict__ out)
{
    const int wave = threadIdx.x >> 6;
    const int lane = threadIdx.x & 63;
    const int b    = blockIdx.x * 4 + wave;
    const u16* row = res + (int64_t)b * N_DIM;
    const int u0 = lane * 8;

    float v[5][8];
    float rstd[5], mean[5];

#pragma unroll
    for (int g = 0; g < 5; ++g) {
        u16x8 raw = *(const u16x8*)(row + g * 512 + u0);
        const float4* bp = (const float4*)(bias + g * 512 + u0);
        float4 b0 = bp[0], b1 = bp[1];
        v[g][0] = bf2f(raw[0]) + b0.x;  v[g][1] = bf2f(raw[1]) + b0.y;
        v[g][2] = bf2f(raw[2]) + b0.z;  v[g][3] = bf2f(raw[3]) + b0.w;
        v[g][4] = bf2f(raw[4]) + b1.x;  v[g][5] = bf2f(raw[5]) + b1.y;
        v[g][6] = bf2f(raw[6]) + b1.z;  v[g][7] = bf2f(raw[7]) + b1.w;
        float s = 0.f, q = 0.f;
#pragma unroll
        for (int j = 0; j < 8; ++j) { s += v[g][j]; q += v[g][j] * v[g][j]; }
#pragma unroll
        for (int off = 1; off < 64; off <<= 1) {
            s += __shfl_xor(s, off);
            q += __shfl_xor(q, off);
        }
        float m   = s * (1.0f / 512.0f);
        float var = q * (1.0f / 512.0f) - m * m;
        mean[g] = m;
        rstd[g] = rsqrtf(var + 1e-5f);
    }

#pragma unroll
    for (int g = 0; g < 5; ++g) {
        const float4* wp = (const float4*)(nw + g * 512 + u0);
        const float4* bp = (const float4*)(nb + g * 512 + u0);
        float4 w0 = wp[0], w1 = wp[1], n0 = bp[0], n1 = bp[1];
        float ws[8] = {w0.x, w0.y, w0.z, w0.w, w1.x, w1.y, w1.z, w1.w};
        float ns[8] = {n0.x, n0.y, n0.z, n0.w, n1.x, n1.y, n1.z, n1.w};
#pragma unroll
        for (int j = 0; j < 8; ++j)
            v[g][j] = (v[g][j] - mean[g]) * rstd[g] * ws[j] + ns[j];
    }

    const float4* c1p = (const float4*)(c1 + (int64_t)b * 512 + u0);
    const float4* c2p = (const float4*)(c2 + (int64_t)b * 512 + u0);
    float4 c1a = c1p[0], c1b = c1p[1], c2a = c2p[0], c2b = c2p[1];
    float c1s[8] = {c1a.x, c1a.y, c1a.z, c1a.w, c1b.x, c1b.y, c1b.z, c1b.w};
    float c2s[8] = {c2a.x, c2a.y, c2a.z, c2a.w, c2b.x, c2b.y, c2b.z, c2b.w};

    float oc[8], oh[8];
#pragma unroll
    for (int j = 0; j < 8; ++j) {
        float ig  = fsig(v[0][j]);
        float jg  = ftanh(v[1][j]);
        float fg  = fsig(v[2][j]);
        float f2g = fsig(v[3][j]);
        float og  = fsig(v[4][j]);
        float cc  = c1s[j] * fg + c2s[j] * f2g + ig * jg;
        oc[j] = cc;
        oh[j] = cc * og;
    }

    float* oC = out + (int64_t)b * 512 + u0;
    float* oH = out + (int64_t)B_DIM * U_DIM + (int64_t)b * 512 + u0;
    ((float4*)oC)[0] = make_float4(oc[0], oc[1], oc[2], oc[3]);
    ((float4*)oC)[1] = make_float4(oc[4], oc[5], oc[6], oc[7]);
    ((float4*)oH)[0] = make_float4(oh[0], oh[1], oh[2], oh[3]);
    ((float4*)oH)[1] = make_float4(oh[4], oh[5], oh[6], oh[7]);
}

// ---------------------------------------------------------------------------
extern "C" void kernel_launch(void* const* d_in, const int* in_sizes, int n_in,
                              void* d_out, int out_size, void* d_ws, size_t ws_size,
                              hipStream_t stream)
{
    const float* inputs = (const float*)d_in[0];
    const float* c1     = (const float*)d_in[1];
    const float* h1     = (const float*)d_in[2];
    const float* c2     = (const float*)d_in[3];
    const float* h2     = (const float*)d_in[4];
    const float* w      = (const float*)d_in[5];
    const float* bias   = (const float*)d_in[6];
    const float* nw     = (const float*)d_in[7];
    const float* nb     = (const float*)d_in[8];
    float* out = (float*)d_out;

    const size_t XB_BYTES = (size_t)B_DIM * K_DIM * 2;   // 50331648
    const size_t WT_BYTES = (size_t)N_DIM * K_DIM * 2;   // 7864320
    u16* xb  = (u16*)d_ws;
    u16* wT  = (u16*)((char*)d_ws + XB_BYTES);
    u16* res = (u16*)((char*)d_ws + XB_BYTES + WT_BYTES);

    cvt_x_kernel<<<(B_DIM * K_DIM / 4 + 255) / 256, 256, 0, stream>>>(inputs, h1, h2, xb);
    cvt_wT_kernel<<<dim3(N_DIM / 32, K_DIM / 32), 256, 0, stream>>>(w, wT);
    gemm_kernel<<<(B_DIM / 128) * (N_DIM / 256), 512, 0, stream>>>(xb, wT, res);
    ln_pointwise_kernel<<<B_DIM / 4, 256, 0, stream>>>(res, bias, c1, c2, nw, nb, out);
}